// Round 7
// baseline (344.623 us; speedup 1.0000x reference)
//
#include <hip/hip_runtime.h>

#define NN 10000
#define EE 160000

#define HB 625            // (EE+255)/256
#define GYR 157           // (NN+63)/64
#define GB128 (11 * GYR)  // 1727
#define GB256 (21 * GYR)  // 3297

typedef __attribute__((ext_vector_type(8))) short bf16x8;
typedef __attribute__((ext_vector_type(4))) float f32x4;
typedef __attribute__((ext_vector_type(2))) float f32x2;
typedef __attribute__((ext_vector_type(8))) float f32x8;
typedef __attribute__((ext_vector_type(16))) float f32x16;

__device__ __forceinline__ short f2b(float f) {
    union { float f; unsigned u; } v; v.f = f;
    unsigned r = v.u + 0x7FFF + ((v.u >> 16) & 1);  // RNE
    return (short)(r >> 16);
}

// --------------------------- prep: weights/x quant + transpose + dst hist
// (counts zeroed by hipMemsetAsync before this kernel; hist hides here)
struct PrepParams {
    const float* tsrc[8];
    short* tdst[8];
    int tN[8];
    int tshift[8];
    int tcum4[9];
    const float* W[4]; const float* al[4]; const float* ar[4];
    short* Wc[4]; int Dl[4]; int base[4];
    const float* We1; const float* ae1; float* vbuf;
    const float* node_feats; short* xb;
    const int* dst; int* counts;
    int bWA, bV, bC, bZ, nblk;
};
__global__ __launch_bounds__(256) void prep_kernel(PrepParams P) {
    int blk = blockIdx.x, tid = threadIdx.x;
    if (blk < P.bWA) {
        int t = blk * 256 + tid;
        if (t >= P.tcum4[8]) return;
        int i = 0;
        #pragma unroll
        for (int j = 1; j < 8; ++j) i += (t >= P.tcum4[j]);
        int local = t - P.tcum4[i];
        int N = P.tN[i], sh = P.tshift[i];
        int k = local >> (sh - 2);
        int nq = local & ((N >> 2) - 1);
        float4 v = *(const float4*)(P.tsrc[i] + (size_t)k * N + nq * 4);
        short* d = P.tdst[i] + (size_t)nq * 4 * 128 + k;
        d[0] = f2b(v.x); d[128] = f2b(v.y); d[256] = f2b(v.z); d[384] = f2b(v.w);
    } else if (blk < P.bV) {
        int bl = blk - P.bWA;
        int l = bl >> 7, within = bl & 127;
        int wv = tid >> 6, ln = tid & 63;
        int wid = within * 4 + wv;
        int k = wid >> 2, h = wid & 3;
        int D = P.Dl[l];
        const float* w = P.W[l] + ((size_t)k * 4 + h) * D;
        const float* a = P.al[l] + (size_t)h * D;
        const float* r = P.ar[l] + (size_t)h * D;
        float sa, sr;
        if (D == 128) {
            float2 w2 = ((const float2*)w)[ln];
            float2 a2 = ((const float2*)a)[ln];
            float2 r2 = ((const float2*)r)[ln];
            sa = w2.x * a2.x + w2.y * a2.y;
            sr = w2.x * r2.x + w2.y * r2.y;
        } else {
            float4 w4 = ((const float4*)w)[ln];
            float4 a4 = ((const float4*)a)[ln];
            float4 r4 = ((const float4*)r)[ln];
            sa = w4.x * a4.x + w4.y * a4.y + w4.z * a4.z + w4.w * a4.w;
            sr = w4.x * r4.x + w4.y * r4.y + w4.z * r4.z + w4.w * r4.w;
        }
        #pragma unroll
        for (int o = 32; o; o >>= 1) { sa += __shfl_xor(sa, o); sr += __shfl_xor(sr, o); }
        if (ln == 0) {
            P.Wc[l][(size_t)(P.base[l] + h) * 128 + k]     = f2b(sa);
            P.Wc[l][(size_t)(P.base[l] + 4 + h) * 128 + k] = f2b(sr);
        }
    } else if (blk < P.bC) {
        int bl = blk - P.bV;
        int wv = tid >> 6, ln = tid & 63;
        int i = bl * 4 + wv;
        #pragma unroll
        for (int h = 0; h < 4; ++h) {
            const float* w = P.We1 + ((size_t)i * 4 + h) * 128;
            const float* a = P.ae1 + (size_t)h * 128;
            float2 w2 = ((const float2*)w)[ln];
            float2 a2 = ((const float2*)a)[ln];
            float s = w2.x * a2.x + w2.y * a2.y;
            #pragma unroll
            for (int o = 32; o; o >>= 1) s += __shfl_xor(s, o);
            if (ln == 0) P.vbuf[i * 4 + h] = s;
        }
    } else if (blk < P.bZ) {
        int t = (blk - P.bC) * 256 + tid;
        if (t < NN * 32) {
            float4 v = ((const float4*)P.node_feats)[t];
            uint2 pk;
            pk.x = (unsigned short)f2b(v.x) | ((unsigned)(unsigned short)f2b(v.y) << 16);
            pk.y = (unsigned short)f2b(v.z) | ((unsigned)(unsigned short)f2b(v.w) << 16);
            ((uint2*)P.xb)[t] = pk;
        }
    } else {
        int e = (blk - P.bZ) * 256 + tid;
        if (e < EE) atomicAdd(&P.counts[P.dst[e]], 1);
    }
}

// ---------------- fused GEMM (operand-swapped: acc holds 4 consecutive COLS
// of one node -> featq packs to one dword store, y/elr are float4 stores;
// 4x fewer C-store instructions than the row-layout epilogue).
template <int D>
__device__ __forceinline__ void gemm_body(const short* __restrict__ A,
                                          const short* __restrict__ Bt,
                                          unsigned char* __restrict__ featq,
                                          float* __restrict__ y,
                                          float* __restrict__ elr,
                                          int M, int bx, int by) {
    constexpr int HD = 4 * D;
    int wave = threadIdx.x >> 6, lane = threadIdx.x & 63;
    int m0 = by * 64;
    int n0 = bx * 64 + wave * 16;
    int r = lane & 15, quad = lane >> 4;
    f32x4 acc[4] = {};
    const short* bp = Bt + (size_t)(n0 + r) * 128 + quad * 8;
    #pragma unroll
    for (int k0 = 0; k0 < 128; k0 += 32) {
        bf16x8 bfrag = *(const bf16x8*)(bp + k0);
        #pragma unroll
        for (int mt = 0; mt < 4; ++mt) {
            int gm = m0 + mt * 16 + r;
            bf16x8 afrag = {};
            if (gm < M) afrag = *(const bf16x8*)(A + (size_t)gm * 128 + k0 + quad * 8);
            // swapped: first operand indexes D-rows (output cols n0+quad*4+rr),
            // second indexes D-cols (nodes gm) -> computes C^T fragment
            acc[mt] = __builtin_amdgcn_mfma_f32_16x16x32_bf16(bfrag, afrag, acc[mt], 0, 0, 0);
        }
    }
    int c4 = n0 + quad * 4;  // 4 consecutive output columns
    #pragma unroll
    for (int mt = 0; mt < 4; ++mt) {
        int gm = m0 + mt * 16 + r;
        if (gm >= M) continue;
        float v0 = acc[mt][0], v1 = acc[mt][1], v2 = acc[mt][2], v3 = acc[mt][3];
        if (c4 < HD) {
            unsigned p = __builtin_amdgcn_cvt_pk_fp8_f32(v0, v1, 0, false);
            p = __builtin_amdgcn_cvt_pk_fp8_f32(v2, v3, p, true);
            *(unsigned*)(featq + (size_t)gm * HD + c4) = p;
        } else if (c4 < HD + D) {
            float4 o; o.x = v0; o.y = v1; o.z = v2; o.w = v3;
            *(float4*)(y + (size_t)gm * D + (c4 - HD)) = o;
        } else if (c4 < HD + D + 8) {
            float4 o; o.x = v0; o.y = v1; o.z = v2; o.w = v3;
            *(float4*)(elr + (size_t)gm * 8 + (c4 - HD - D)) = o;
        }
    }
}

template <int D>
__global__ __launch_bounds__(256) void gemm_fused(const short* __restrict__ A,
                                                  const short* __restrict__ Bt,
                                                  unsigned char* __restrict__ featq,
                                                  float* __restrict__ y,
                                                  float* __restrict__ elr,
                                                  int M) {
    gemm_body<D>(A, Bt, featq, y, elr, M, blockIdx.x, blockIdx.y);
}

// register-staged scan (single block); n=NN, NN%4==0 so int4 path covers all
__device__ __forceinline__ void scan_body(const int* __restrict__ counts,
                                          int* __restrict__ off,
                                          int* __restrict__ cur) {
    __shared__ int part[256];
    const int n = NN;
    int tid = threadIdx.x;
    int lo = tid * 40;
    int4 r[10];
    int s = 0;
    #pragma unroll
    for (int q = 0; q < 10; ++q) {
        int idx = lo + q * 4;
        int4 v = make_int4(0, 0, 0, 0);
        if (idx + 3 < n) v = *(const int4*)(counts + idx);
        r[q] = v;
        s += v.x + v.y + v.z + v.w;
    }
    part[tid] = s;
    __syncthreads();
    for (int o = 1; o < 256; o <<= 1) {
        int v = (tid >= o) ? part[tid - o] : 0;
        __syncthreads();
        part[tid] += v;
        __syncthreads();
    }
    int run = tid ? part[tid - 1] : 0;
    #pragma unroll
    for (int q = 0; q < 10; ++q) {
        int4 v = r[q], o4;
        o4.x = run; run += v.x;
        o4.y = run; run += v.y;
        o4.z = run; run += v.z;
        o4.w = run; run += v.w;
        int idx = lo + q * 4;
        if (idx + 3 < n) { *(int4*)(off + idx) = o4; *(int4*)(cur + idx) = o4; }
    }
    if (tid == 255) off[n] = part[255];
}

// kernel2: unsorted edge-extra dot + layer-1 GEMM + scan (last block).
__global__ __launch_bounds__(256) void gemm1_extra_scan(const float* __restrict__ ef,
                                                        const float* __restrict__ vbuf,
                                                        float* __restrict__ extraU,
                                                        const short* __restrict__ A,
                                                        const short* __restrict__ Bt,
                                                        unsigned char* __restrict__ featq,
                                                        float* __restrict__ y,
                                                        float* __restrict__ elr,
                                                        const int* __restrict__ counts,
                                                        int* __restrict__ off,
                                                        int* __restrict__ cur) {
    int vb = blockIdx.x;
    if (vb < HB) {
        __shared__ float vs[256];
        vs[threadIdx.x] = vbuf[threadIdx.x];
        __syncthreads();
        int e = vb * 256 + threadIdx.x;
        if (e < EE) {
            float a0 = 0.f, a1 = 0.f, a2 = 0.f, a3 = 0.f;
            const float4* e4 = (const float4*)(ef + (size_t)e * 64);
            #pragma unroll
            for (int c = 0; c < 16; ++c) {
                float4 x = e4[c];
                int b = c * 16;
                a0 += x.x * vs[b + 0] + x.y * vs[b + 4] + x.z * vs[b + 8] + x.w * vs[b + 12];
                a1 += x.x * vs[b + 1] + x.y * vs[b + 5] + x.z * vs[b + 9] + x.w * vs[b + 13];
                a2 += x.x * vs[b + 2] + x.y * vs[b + 6] + x.z * vs[b + 10] + x.w * vs[b + 14];
                a3 += x.x * vs[b + 3] + x.y * vs[b + 7] + x.z * vs[b + 11] + x.w * vs[b + 15];
            }
            float4 o; o.x = a0; o.y = a1; o.z = a2; o.w = a3;
            *(float4*)(extraU + (size_t)e * 4) = o;
        }
    } else if (vb < HB + GB128) {
        int b = vb - HB;
        gemm_body<128>(A, Bt, featq, y, elr, NN, b % 11, b / 11);
    } else {
        scan_body(counts, off, cur);
    }
}

// fill: permute ssrc + precomputed extraU into CSR order (16B per edge)
__global__ __launch_bounds__(256) void fill_extra(const int* __restrict__ src,
                                                  const int* __restrict__ dst,
                                                  int* __restrict__ cur,
                                                  const float* __restrict__ extraU,
                                                  int* __restrict__ ssrc,
                                                  float* __restrict__ extra, int E) {
    int e = blockIdx.x * 256 + threadIdx.x;
    if (e >= E) return;
    int p = atomicAdd(&cur[dst[e]], 1);
    ssrc[p] = src[e];
    *(float4*)(extra + (size_t)p * 4) = *(const float4*)(extraU + (size_t)e * 4);
}

// -------------------- gather accumulators: SSA vector values, by-value.
// (R2 lesson: float acc[16] passed as float* failed SROA -> scratch ->
//  620MB/dispatch of spill traffic. Never pass local arrays by pointer.)
__device__ __forceinline__ f32x16 accum16q(f32x16 a, uint4 v, float w) {
    f32x2 p;
    p = __builtin_amdgcn_cvt_pk_f32_fp8(v.x, false); a[0] += w * p.x; a[1] += w * p.y;
    p = __builtin_amdgcn_cvt_pk_f32_fp8(v.x, true);  a[2] += w * p.x; a[3] += w * p.y;
    p = __builtin_amdgcn_cvt_pk_f32_fp8(v.y, false); a[4] += w * p.x; a[5] += w * p.y;
    p = __builtin_amdgcn_cvt_pk_f32_fp8(v.y, true);  a[6] += w * p.x; a[7] += w * p.y;
    p = __builtin_amdgcn_cvt_pk_f32_fp8(v.z, false); a[8] += w * p.x; a[9] += w * p.y;
    p = __builtin_amdgcn_cvt_pk_f32_fp8(v.z, true);  a[10] += w * p.x; a[11] += w * p.y;
    p = __builtin_amdgcn_cvt_pk_f32_fp8(v.w, false); a[12] += w * p.x; a[13] += w * p.y;
    p = __builtin_amdgcn_cvt_pk_f32_fp8(v.w, true);  a[14] += w * p.x; a[15] += w * p.y;
    return a;
}

// ---------------- transposed (h,j) softmax for deg<=64, returned by value.
struct SM64 { float ev0, ev1, ev2, ev3; int sx0, sx1, sx2, sx3; float sc; };

template <bool HAS_EXTRA>
__device__ __forceinline__ SM64 softmax64(int r0, int deg, int h, int jh, float erh,
                                          const float* __restrict__ elr,
                                          const float* __restrict__ extra,
                                          const int* __restrict__ ssrc) {
    SM64 R;
    float a0 = -1e30f, a1 = -1e30f, a2 = -1e30f, a3 = -1e30f;
    int sx0 = 0, sx1 = 0, sx2 = 0, sx3 = 0;
    auto lg = [&](int j, int& sx, float& a) {
        if (j < deg) {
            int idx = r0 + j;
            sx = ssrc[idx];
            float v = elr[(size_t)sx * 8 + h] + erh;
            if (HAS_EXTRA) v += extra[(size_t)idx * 4 + h];
            a = v > 0.f ? v : 0.2f * v;
        }
    };
    lg(jh, sx0, a0);
    if (deg > 16) lg(jh + 16, sx1, a1);
    if (deg > 32) lg(jh + 32, sx2, a2);
    if (deg > 48) lg(jh + 48, sx3, a3);
    float m = fmaxf(fmaxf(a0, a1), fmaxf(a2, a3));
    #pragma unroll
    for (int o = 1; o < 16; o <<= 1) m = fmaxf(m, __shfl_xor(m, o));
    R.ev0 = __expf(a0 - m); R.ev1 = __expf(a1 - m);
    R.ev2 = __expf(a2 - m); R.ev3 = __expf(a3 - m);
    float ss = R.ev0 + R.ev1 + R.ev2 + R.ev3;
    #pragma unroll
    for (int o = 1; o < 16; o <<= 1) ss += __shfl_xor(ss, o);
    R.sc = 0.25f / (ss + 1e-9f);
    R.sx0 = sx0; R.sx1 = sx1; R.sx2 = sx2; R.sx3 = sx3;
    return R;
}

// ---------------- D=128 layers: 1 wave/node; DUAL-EDGE gather: 32 lanes x
// 16B cover a 512B row, lane-group g=ln>>5 takes edge c+g -> per 2 edges:
// 1 uint4 load + 2 shfl (vs 2 loads + 4 shfl in the single-edge form).
template <bool HAS_EXTRA>
__global__ __launch_bounds__(256) void gat128(const unsigned char* __restrict__ featq,
                                              const float* __restrict__ elr,
                                              const float* __restrict__ extra,
                                              const int* __restrict__ ssrc,
                                              const int* __restrict__ off,
                                              const float* __restrict__ yres,
                                              short* __restrict__ ybf) {
    int wv = threadIdx.x >> 6, ln = threadIdx.x & 63;
    int n = blockIdx.x * 4 + wv;
    int r0 = off[n], deg = off[n + 1] - r0;
    int h = ln >> 4, jh = ln & 15;          // softmax role
    int g = ln >> 5, l5 = ln & 31;          // gather role
    int hw = (l5 >> 3) << 4;                // gather head's softmax-lane base
    float erh = elr[(size_t)n * 8 + 4 + h];
    f32x16 acc = {};
    const unsigned char* basep = featq + l5 * 16;
    float scl;

    if (deg <= 64) {
        SM64 R = softmax64<HAS_EXTRA>(r0, deg, h, jh, erh, elr, extra, ssrc);
        scl = __shfl(R.sc, hw);             // head (l5>>3)'s scale
        auto blk16 = [&](float ee, int si, int cnt) {  // cnt in [1,16]
            int c = 0;
            for (; c + 4 <= cnt; c += 4) {
                float w0 = __shfl(ee, hw | (c + g));
                float w1 = __shfl(ee, hw | (c + 2 + g));
                int s0 = __shfl(si, c + g);
                int s1 = __shfl(si, c + 2 + g);
                uint4 v0 = *(const uint4*)(basep + (size_t)s0 * 512);
                uint4 v1 = *(const uint4*)(basep + (size_t)s1 * 512);
                acc = accum16q(acc, v0, w0);
                acc = accum16q(acc, v1, w1);
            }
            for (; c < cnt; c += 2) {
                int j = c + g;
                float msk = j < cnt ? 1.f : 0.f;
                int jc = j < cnt ? j : c;
                float w = __shfl(ee, hw | jc) * msk;
                int s = __shfl(si, jc);
                uint4 v = *(const uint4*)(basep + (size_t)s * 512);
                acc = accum16q(acc, v, w);
            }
        };
        blk16(R.ev0, R.sx0, deg < 16 ? deg : 16);
        if (deg > 16) blk16(R.ev1, R.sx1, deg < 32 ? deg - 16 : 16);
        if (deg > 32) blk16(R.ev2, R.sx2, deg < 48 ? deg - 32 : 16);
        if (deg > 48) blk16(R.ev3, R.sx3, deg - 48);
    } else {
        // generic fallback (deg>64, effectively never): per-lane gather-head
        int hg = l5 >> 3;
        float erg = elr[(size_t)n * 8 + 4 + hg];
        auto lgt = [&](int c) {
            int s = ssrc[r0 + c];
            float v = elr[(size_t)s * 8 + hg] + erg;
            if (HAS_EXTRA) v += extra[(size_t)(r0 + c) * 4 + hg];
            return v > 0.f ? v : 0.2f * v;
        };
        float m = -1e30f;
        for (int c = 0; c < deg; ++c) m = fmaxf(m, lgt(c));
        float ss = 0.f;
        for (int c = 0; c < deg; ++c) ss += __expf(lgt(c) - m);
        scl = 0.25f / (ss + 1e-9f);
        for (int c = g; c < deg; c += 2) {
            float w = __expf(lgt(c) - m);
            int s = ssrc[r0 + c];
            uint4 v = *(const uint4*)(basep + (size_t)s * 512);
            acc = accum16q(acc, v, w);
        }
    }

    // per-lane scl is its gather-head's scale; sum over h (xor8,16) + g (xor32)
    f32x16 t;
    #pragma unroll
    for (int i = 0; i < 16; ++i) {
        float v = acc[i] * scl;
        v += __shfl_xor(v, 8);
        v += __shfl_xor(v, 16);
        v += __shfl_xor(v, 32);
        t[i] = v;
    }
    if (ln < 8) {
        int d0 = ln * 16;
        const float* yr = yres + (size_t)n * 128 + d0;
        unsigned pk[8];
        #pragma unroll
        for (int q = 0; q < 8; ++q) {
            float ya = yr[2 * q], yb = yr[2 * q + 1];
            float o0 = fmaxf(ya + t[2 * q], 0.f);
            float o1 = fmaxf(yb + t[2 * q + 1], 0.f);
            pk[q] = (unsigned short)f2b(o0) | ((unsigned)(unsigned short)f2b(o1) << 16);
        }
        uint4 pa, pb;
        pa.x = pk[0]; pa.y = pk[1]; pa.z = pk[2]; pa.w = pk[3];
        pb.x = pk[4]; pb.y = pk[5]; pb.z = pk[6]; pb.w = pk[7];
        *(uint4*)(ybf + (size_t)n * 128 + d0) = pa;
        *(uint4*)(ybf + (size_t)n * 128 + d0 + 8) = pb;
    }
}

// ---------------- D=256 layer 4: 2 waves/node (even/odd edges), transposed
// softmax per wave, slot-blocked gather, 16B/lane row, halves via padded LDS.
// (R3-proven form, unchanged.)
__global__ __launch_bounds__(256) void gat256(const unsigned char* __restrict__ featq,
                                              const float* __restrict__ elr,
                                              const int* __restrict__ ssrc,
                                              const int* __restrict__ off,
                                              const float* __restrict__ yres,
                                              float* __restrict__ yout) {
    __shared__ float red[2][16 * 17];
    int wv = threadIdx.x >> 6, ln = threadIdx.x & 63;
    int slot = wv >> 1, half = wv & 1;
    int n = blockIdx.x * 2 + slot;
    int r0 = off[n], deg = off[n + 1] - r0;
    int h = ln >> 4, jh = ln & 15;
    float erh = elr[(size_t)n * 8 + 4 + h];
    f32x16 acc = {};
    const unsigned char* basep = featq + ln * 16;
    float sc;

    if (deg <= 64) {
        SM64 R = softmax64<false>(r0, deg, h, jh, erh, elr, nullptr, ssrc);
        sc = R.sc;
        int hh = h << 4;
        auto blk16 = [&](float ee, int si, int cnt) {  // edges half,half+2,.. < cnt
            int c = half;
            for (; c + 6 < cnt; c += 8) {
                float w0 = __shfl(ee, hh | c),       w1 = __shfl(ee, hh | (c + 2));
                float w2 = __shfl(ee, hh | (c + 4)), w3 = __shfl(ee, hh | (c + 6));
                int s0 = __shfl(si, c),     s1 = __shfl(si, c + 2);
                int s2 = __shfl(si, c + 4), s3 = __shfl(si, c + 6);
                uint4 v0 = *(const uint4*)(basep + (size_t)s0 * 1024);
                uint4 v1 = *(const uint4*)(basep + (size_t)s1 * 1024);
                uint4 v2 = *(const uint4*)(basep + (size_t)s2 * 1024);
                uint4 v3 = *(const uint4*)(basep + (size_t)s3 * 1024);
                acc = accum16q(acc, v0, w0); acc = accum16q(acc, v1, w1);
                acc = accum16q(acc, v2, w2); acc = accum16q(acc, v3, w3);
            }
            for (; c < cnt; c += 2) {
                float w = __shfl(ee, hh | c);
                int s = __shfl(si, c);
                uint4 v = *(const uint4*)(basep + (size_t)s * 1024);
                acc = accum16q(acc, v, w);
            }
        };
        blk16(R.ev0, R.sx0, deg < 16 ? deg : 16);
        if (deg > 16) blk16(R.ev1, R.sx1, (deg < 32 ? deg : 32) - 16);
        if (deg > 32) blk16(R.ev2, R.sx2, (deg < 48 ? deg : 48) - 32);
        if (deg > 48) blk16(R.ev3, R.sx3, deg - 48);
    } else {
        auto lgt = [&](int c) {
            int s = ssrc[r0 + c];
            float v = elr[(size_t)s * 8 + h] + erh;
            return v > 0.f ? v : 0.2f * v;
        };
        float m = -1e30f;
        for (int c = 0; c < deg; ++c) m = fmaxf(m, lgt(c));
        float ss = 0.f;
        for (int c = 0; c < deg; ++c) ss += __expf(lgt(c) - m);
        sc = 0.25f / (ss + 1e-9f);
        for (int c = half; c < deg; c += 2) {
            float w = __expf(lgt(c) - m);
            int s = ssrc[r0 + c];
            uint4 v = *(const uint4*)(basep + (size_t)s * 1024);
            acc = accum16q(acc, v, w);
        }
    }

    // per-lane sc is correct for own head; head-mean via xor16+xor32
    f32x16 t;
    #pragma unroll
    for (int i = 0; i < 16; ++i) {
        float v = acc[i] * sc;
        v += __shfl_xor(v, 16);
        v += __shfl_xor(v, 32);
        t[i] = v;
    }
    if (half == 1 && ln < 16) {
        #pragma unroll
        for (int i = 0; i < 16; ++i) red[slot][ln * 17 + i] = t[i];
    }
    __syncthreads();
    if (half == 0 && ln < 16) {
        const float* yr = yres + (size_t)n * 256 + ln * 16;
        float* yo = yout + (size_t)n * 256 + ln * 16;
        #pragma unroll
        for (int q = 0; q < 4; ++q) {
            float4 ya = *(const float4*)(yr + 4 * q);
            float4 ov;
            ov.x = fmaxf(ya.x + t[4 * q + 0] + red[slot][ln * 17 + 4 * q + 0], 0.f);
            ov.y = fmaxf(ya.y + t[4 * q + 1] + red[slot][ln * 17 + 4 * q + 1], 0.f);
            ov.z = fmaxf(ya.z + t[4 * q + 2] + red[slot][ln * 17 + 4 * q + 2], 0.f);
            ov.w = fmaxf(ya.w + t[4 * q + 3] + red[slot][ln * 17 + 4 * q + 3], 0.f);
            *(float4*)(yo + 4 * q) = ov;
        }
    }
}

// ---------------------------------------------------------------- host side
extern "C" void kernel_launch(void* const* d_in, const int* in_sizes, int n_in,
                              void* d_out, int out_size, void* d_ws, size_t ws_size,
                              hipStream_t stream) {
    const float* node_feats = (const float*)d_in[0];
    const float* edge_feats = (const float*)d_in[1];
    const int*   src        = (const int*)d_in[2];
    const int*   dst        = (const int*)d_in[3];
    const float* W1   = (const float*)d_in[4];
    const float* We1  = (const float*)d_in[5];
    const float* al1  = (const float*)d_in[6];
    const float* ar1  = (const float*)d_in[7];
    const float* ae1  = (const float*)d_in[8];
    const float* res1 = (const float*)d_in[9];
    const float* W2   = (const float*)d_in[10];
    const float* al2  = (const float*)d_in[11];
    const float* ar2  = (const float*)d_in[12];
    const float* res2 = (const float*)d_in[13];
    const float* W3   = (const float*)d_in[14];
    const float* al3  = (const float*)d_in[15];
    const float* ar3  = (const float*)d_in[16];
    const float* res3 = (const float*)d_in[17];
    const float* W4   = (const float*)d_in[18];
    const float* al4  = (const float*)d_in[19];
    const float* ar4  = (const float*)d_in[20];
    const float* res4 = (const float*)d_in[21];

    char* ws = (char*)d_ws;
    auto alloc = [&](size_t bytes) -> char* {
        char* p = ws;
        ws += (bytes + 255) & ~(size_t)255;
        return p;
    };
    int*   counts  = (int*)alloc((size_t)NN * 4);
    int*   offsets = (int*)alloc((size_t)(NN + 1) * 4);
    int*   cursor  = (int*)alloc((size_t)(NN + 1) * 4);
    int*   ssrc    = (int*)alloc((size_t)EE * 4);
    unsigned char* featq = (unsigned char*)alloc((size_t)NN * 1024);
    float* xA      = (float*)alloc((size_t)NN * 128 * 4);
    short* xb      = (short*)alloc((size_t)NN * 128 * 2);
    float* elr     = (float*)alloc((size_t)NN * 8 * 4);
    float* extra   = (float*)alloc((size_t)EE * 4 * 4);
    float* extraU  = (float*)alloc((size_t)EE * 4 * 4);
    float* vbuf    = (float*)alloc(1024);
    short* Wc1     = (short*)alloc((size_t)704 * 128 * 2);
    short* Wc2     = (short*)alloc((size_t)704 * 128 * 2);
    short* Wc3     = (short*)alloc((size_t)704 * 128 * 2);
    short* Wc4     = (short*)alloc((size_t)1344 * 128 * 2);

    PrepParams P;
    P.tsrc[0] = W1;   P.tdst[0] = Wc1;              P.tN[0] = 512;  P.tshift[0] = 9;
    P.tsrc[1] = W2;   P.tdst[1] = Wc2;              P.tN[1] = 512;  P.tshift[1] = 9;
    P.tsrc[2] = W3;   P.tdst[2] = Wc3;              P.tN[2] = 512;  P.tshift[2] = 9;
    P.tsrc[3] = W4;   P.tdst[3] = Wc4;              P.tN[3] = 1024; P.tshift[3] = 10;
    P.tsrc[4] = res1; P.tdst[4] = Wc1 + 512 * 128;  P.tN[4] = 128;  P.tshift[4] = 7;
    P.tsrc[5] = res2; P.tdst[5] = Wc2 + 512 * 128;  P.tN[5] = 128;  P.tshift[5] = 7;
    P.tsrc[6] = res3; P.tdst[6] = Wc3 + 512 * 128;  P.tN[6] = 128;  P.tshift[6] = 7;
    P.tsrc[7] = res4; P.tdst[7] = Wc4 + 1024 * 128; P.tN[7] = 256;  P.tshift[7] = 8;
    P.tcum4[0] = 0;
    for (int i = 0; i < 8; ++i) P.tcum4[i + 1] = P.tcum4[i] + P.tN[i] * 128 / 4;
    P.W[0] = W1; P.W[1] = W2; P.W[2] = W3; P.W[3] = W4;
    P.al[0] = al1; P.al[1] = al2; P.al[2] = al3; P.al[3] = al4;
    P.ar[0] = ar1; P.ar[1] = ar2; P.ar[2] = ar3; P.ar[3] = ar4;
    P.Wc[0] = Wc1; P.Wc[1] = Wc2; P.Wc[2] = Wc3; P.Wc[3] = Wc4;
    P.Dl[0] = 128; P.Dl[1] = 128; P.Dl[2] = 128; P.Dl[3] = 256;
    P.base[0] = 640; P.base[1] = 640; P.base[2] = 640; P.base[3] = 1280;
    P.We1 = We1; P.ae1 = ae1; P.vbuf = vbuf;
    P.node_feats = node_feats; P.xb = xb;
    P.dst = dst; P.counts = counts;
    P.bWA = (P.tcum4[8] + 255) / 256;
    P.bV  = P.bWA + 512;
    P.bC  = P.bV + 16;
    P.bZ  = P.bC + (NN * 32 + 255) / 256;
    P.nblk = P.bZ + HB;  // hist blocks replace the old counts-zero blocks

    float* out = (float*)d_out;

    // counts zeroed by memset (graph-capturable); hist hides inside prep
    hipMemsetAsync(counts, 0, (size_t)NN * 4, stream);
    prep_kernel<<<P.nblk, 256, 0, stream>>>(P);
    gemm1_extra_scan<<<HB + GB128 + 1, 256, 0, stream>>>(
        edge_feats, vbuf, extraU, xb, Wc1, featq, xA, elr, counts, offsets, cursor);
    fill_extra<<<HB, 256, 0, stream>>>(src, dst, cursor, extraU, ssrc, extra, EE);

    dim3 g128(11, GYR);
    dim3 g256(21, GYR);
    // ---- layer 1 gather
    gat128<true><<<NN / 4, 256, 0, stream>>>(featq, elr, extra, ssrc, offsets, xA, xb);
    // ---- layer 2
    gemm_fused<128><<<g128, 256, 0, stream>>>(xb, Wc2, featq, xA, elr, NN);
    gat128<false><<<NN / 4, 256, 0, stream>>>(featq, elr, nullptr, ssrc, offsets, xA, xb);
    // ---- layer 3
    gemm_fused<128><<<g128, 256, 0, stream>>>(xb, Wc3, featq, xA, elr, NN);
    gat128<false><<<NN / 4, 256, 0, stream>>>(featq, elr, nullptr, ssrc, offsets, xA, xb);
    // ---- layer 4
    gemm_fused<256><<<g256, 256, 0, stream>>>(xb, Wc4, featq, out, elr, NN);
    gat256<<<NN / 2, 256, 0, stream>>>(featq, elr, ssrc, offsets, out, out);
}

// Round 8
// 332.952 us; speedup vs baseline: 1.0351x; 1.0351x over previous
//
#include <hip/hip_runtime.h>

#define NN 10000
#define EE 160000

#define HB 625            // (EE+255)/256
#define GYR 157           // (NN+63)/64
#define GB128 (11 * GYR)  // 1727
#define GB256 (21 * GYR)  // 3297

typedef __attribute__((ext_vector_type(8))) short bf16x8;
typedef __attribute__((ext_vector_type(4))) float f32x4;
typedef __attribute__((ext_vector_type(2))) float f32x2;
typedef __attribute__((ext_vector_type(8))) float f32x8;
typedef __attribute__((ext_vector_type(16))) float f32x16;

__device__ __forceinline__ short f2b(float f) {
    union { float f; unsigned u; } v; v.f = f;
    unsigned r = v.u + 0x7FFF + ((v.u >> 16) & 1);  // RNE
    return (short)(r >> 16);
}
// fp8 e4m3 (OCP) encode via HW converter; returns low byte
__device__ __forceinline__ unsigned char f2q(float f) {
    return (unsigned char)(__builtin_amdgcn_cvt_pk_fp8_f32(f, f, 0, false) & 0xFF);
}

// --------------------------- prep: weights/x quant + transpose + dst hist
// (counts zeroed by hipMemsetAsync before this kernel; hist hides here)
struct PrepParams {
    const float* tsrc[8];
    short* tdst[8];
    int tN[8];
    int tshift[8];
    int tcum4[9];
    const float* W[4]; const float* al[4]; const float* ar[4];
    short* Wc[4]; int Dl[4]; int base[4];
    const float* We1; const float* ae1; float* vbuf;
    const float* node_feats; short* xb;
    const int* dst; int* counts;
    int bWA, bV, bC, bZ, nblk;
};
__global__ __launch_bounds__(256) void prep_kernel(PrepParams P) {
    int blk = blockIdx.x, tid = threadIdx.x;
    if (blk < P.bWA) {
        int t = blk * 256 + tid;
        if (t >= P.tcum4[8]) return;
        int i = 0;
        #pragma unroll
        for (int j = 1; j < 8; ++j) i += (t >= P.tcum4[j]);
        int local = t - P.tcum4[i];
        int N = P.tN[i], sh = P.tshift[i];
        int k = local >> (sh - 2);
        int nq = local & ((N >> 2) - 1);
        float4 v = *(const float4*)(P.tsrc[i] + (size_t)k * N + nq * 4);
        short* d = P.tdst[i] + (size_t)nq * 4 * 128 + k;
        d[0] = f2b(v.x); d[128] = f2b(v.y); d[256] = f2b(v.z); d[384] = f2b(v.w);
    } else if (blk < P.bV) {
        int bl = blk - P.bWA;
        int l = bl >> 7, within = bl & 127;
        int wv = tid >> 6, ln = tid & 63;
        int wid = within * 4 + wv;
        int k = wid >> 2, h = wid & 3;
        int D = P.Dl[l];
        const float* w = P.W[l] + ((size_t)k * 4 + h) * D;
        const float* a = P.al[l] + (size_t)h * D;
        const float* r = P.ar[l] + (size_t)h * D;
        float sa, sr;
        if (D == 128) {
            float2 w2 = ((const float2*)w)[ln];
            float2 a2 = ((const float2*)a)[ln];
            float2 r2 = ((const float2*)r)[ln];
            sa = w2.x * a2.x + w2.y * a2.y;
            sr = w2.x * r2.x + w2.y * r2.y;
        } else {
            float4 w4 = ((const float4*)w)[ln];
            float4 a4 = ((const float4*)a)[ln];
            float4 r4 = ((const float4*)r)[ln];
            sa = w4.x * a4.x + w4.y * a4.y + w4.z * a4.z + w4.w * a4.w;
            sr = w4.x * r4.x + w4.y * r4.y + w4.z * r4.z + w4.w * r4.w;
        }
        #pragma unroll
        for (int o = 32; o; o >>= 1) { sa += __shfl_xor(sa, o); sr += __shfl_xor(sr, o); }
        if (ln == 0) {
            P.Wc[l][(size_t)(P.base[l] + h) * 128 + k]     = f2b(sa);
            P.Wc[l][(size_t)(P.base[l] + 4 + h) * 128 + k] = f2b(sr);
        }
    } else if (blk < P.bC) {
        int bl = blk - P.bV;
        int wv = tid >> 6, ln = tid & 63;
        int i = bl * 4 + wv;
        #pragma unroll
        for (int h = 0; h < 4; ++h) {
            const float* w = P.We1 + ((size_t)i * 4 + h) * 128;
            const float* a = P.ae1 + (size_t)h * 128;
            float2 w2 = ((const float2*)w)[ln];
            float2 a2 = ((const float2*)a)[ln];
            float s = w2.x * a2.x + w2.y * a2.y;
            #pragma unroll
            for (int o = 32; o; o >>= 1) s += __shfl_xor(s, o);
            if (ln == 0) P.vbuf[i * 4 + h] = s;
        }
    } else if (blk < P.bZ) {
        int t = (blk - P.bC) * 256 + tid;
        if (t < NN * 32) {
            float4 v = ((const float4*)P.node_feats)[t];
            uint2 pk;
            pk.x = (unsigned short)f2b(v.x) | ((unsigned)(unsigned short)f2b(v.y) << 16);
            pk.y = (unsigned short)f2b(v.z) | ((unsigned)(unsigned short)f2b(v.w) << 16);
            ((uint2*)P.xb)[t] = pk;
        }
    } else {
        int e = (blk - P.bZ) * 256 + tid;
        if (e < EE) atomicAdd(&P.counts[P.dst[e]], 1);
    }
}

// ---------------- fused GEMM: feat (fp8 e4m3) + res (f32) + el/er (f32)
// (R6-proven row-layout form; R7's operand swap regressed and is reverted.)
template <int D>
__device__ __forceinline__ void gemm_body(const short* __restrict__ A,
                                          const short* __restrict__ Bt,
                                          unsigned char* __restrict__ featq,
                                          float* __restrict__ y,
                                          float* __restrict__ elr,
                                          int M, int bx, int by) {
    constexpr int HD = 4 * D;
    int wave = threadIdx.x >> 6, lane = threadIdx.x & 63;
    int m0 = by * 64;
    int n0 = bx * 64 + wave * 16;
    int r = lane & 15, quad = lane >> 4;
    f32x4 acc[4] = {};
    const short* bp = Bt + (size_t)(n0 + r) * 128 + quad * 8;
    #pragma unroll
    for (int k0 = 0; k0 < 128; k0 += 32) {
        bf16x8 bfrag = *(const bf16x8*)(bp + k0);
        #pragma unroll
        for (int mt = 0; mt < 4; ++mt) {
            int gm = m0 + mt * 16 + r;
            bf16x8 afrag = {};
            if (gm < M) afrag = *(const bf16x8*)(A + (size_t)gm * 128 + k0 + quad * 8);
            acc[mt] = __builtin_amdgcn_mfma_f32_16x16x32_bf16(afrag, bfrag, acc[mt], 0, 0, 0);
        }
    }
    int col = n0 + r;
    #pragma unroll
    for (int mt = 0; mt < 4; ++mt) {
        #pragma unroll
        for (int rr = 0; rr < 4; ++rr) {
            int gm = m0 + mt * 16 + quad * 4 + rr;
            if (gm >= M) continue;
            float v = acc[mt][rr];
            if (col < HD)              featq[(size_t)gm * HD + col] = f2q(v);
            else if (col < HD + D)     y[(size_t)gm * D + (col - HD)] = v;
            else if (col < HD + D + 8) elr[(size_t)gm * 8 + (col - HD - D)] = v;
        }
    }
}

template <int D>
__global__ __launch_bounds__(256) void gemm_fused(const short* __restrict__ A,
                                                  const short* __restrict__ Bt,
                                                  unsigned char* __restrict__ featq,
                                                  float* __restrict__ y,
                                                  float* __restrict__ elr,
                                                  int M) {
    gemm_body<D>(A, Bt, featq, y, elr, M, blockIdx.x, blockIdx.y);
}

// register-staged scan (single block) + degree counting-sort (descending).
// nodeperm: node ids ordered by deg desc -> gat blocks get equal-deg waves
// and high-deg blocks launch first (short-block tail).
__device__ __forceinline__ void scan_body(const int* __restrict__ counts,
                                          int* __restrict__ off,
                                          int* __restrict__ cur,
                                          int* __restrict__ nodeperm) {
    __shared__ int part[256];
    __shared__ int hist[64], hbase[64], hcnt[64];
    const int n = NN;
    int tid = threadIdx.x;
    if (tid < 64) { hist[tid] = 0; hcnt[tid] = 0; }
    __syncthreads();
    int lo = tid * 40;
    int4 r[10];
    int s = 0;
    #pragma unroll
    for (int q = 0; q < 10; ++q) {
        int idx = lo + q * 4;
        int4 v = make_int4(0, 0, 0, 0);
        if (idx + 3 < n) v = *(const int4*)(counts + idx);
        r[q] = v;
        s += v.x + v.y + v.z + v.w;
        atomicAdd(&hist[v.x < 63 ? v.x : 63], 1);
        atomicAdd(&hist[v.y < 63 ? v.y : 63], 1);
        atomicAdd(&hist[v.z < 63 ? v.z : 63], 1);
        atomicAdd(&hist[v.w < 63 ? v.w : 63], 1);
    }
    part[tid] = s;
    __syncthreads();
    for (int o = 1; o < 256; o <<= 1) {
        int v = (tid >= o) ? part[tid - o] : 0;
        __syncthreads();
        part[tid] += v;
        __syncthreads();
    }
    int run = tid ? part[tid - 1] : 0;
    #pragma unroll
    for (int q = 0; q < 10; ++q) {
        int4 v = r[q], o4;
        o4.x = run; run += v.x;
        o4.y = run; run += v.y;
        o4.z = run; run += v.z;
        o4.w = run; run += v.w;
        int idx = lo + q * 4;
        if (idx + 3 < n) { *(int4*)(off + idx) = o4; *(int4*)(cur + idx) = o4; }
    }
    if (tid == 255) off[n] = part[255];
    // descending bases: hbase[b] = sum of hist[b'] for b' > b
    if (tid < 64) {
        int acc = 0;
        for (int b2 = tid + 1; b2 < 64; ++b2) acc += hist[b2];
        hbase[tid] = acc;
    }
    __syncthreads();
    #pragma unroll
    for (int q = 0; q < 10; ++q) {
        int4 v = r[q];
        int idx = lo + q * 4;
        int b0 = v.x < 63 ? v.x : 63;
        int b1 = v.y < 63 ? v.y : 63;
        int b2 = v.z < 63 ? v.z : 63;
        int b3 = v.w < 63 ? v.w : 63;
        nodeperm[hbase[b0] + atomicAdd(&hcnt[b0], 1)] = idx;
        nodeperm[hbase[b1] + atomicAdd(&hcnt[b1], 1)] = idx + 1;
        nodeperm[hbase[b2] + atomicAdd(&hcnt[b2], 1)] = idx + 2;
        nodeperm[hbase[b3] + atomicAdd(&hcnt[b3], 1)] = idx + 3;
    }
}

// kernel2: unsorted edge-extra dot + layer-1 GEMM + scan/sort (last block).
__global__ __launch_bounds__(256) void gemm1_extra_scan(const float* __restrict__ ef,
                                                        const float* __restrict__ vbuf,
                                                        float* __restrict__ extraU,
                                                        const short* __restrict__ A,
                                                        const short* __restrict__ Bt,
                                                        unsigned char* __restrict__ featq,
                                                        float* __restrict__ y,
                                                        float* __restrict__ elr,
                                                        const int* __restrict__ counts,
                                                        int* __restrict__ off,
                                                        int* __restrict__ cur,
                                                        int* __restrict__ nodeperm) {
    int vb = blockIdx.x;
    if (vb < HB) {
        __shared__ float vs[256];
        vs[threadIdx.x] = vbuf[threadIdx.x];
        __syncthreads();
        int e = vb * 256 + threadIdx.x;
        if (e < EE) {
            float a0 = 0.f, a1 = 0.f, a2 = 0.f, a3 = 0.f;
            const float4* e4 = (const float4*)(ef + (size_t)e * 64);
            #pragma unroll
            for (int c = 0; c < 16; ++c) {
                float4 x = e4[c];
                int b = c * 16;
                a0 += x.x * vs[b + 0] + x.y * vs[b + 4] + x.z * vs[b + 8] + x.w * vs[b + 12];
                a1 += x.x * vs[b + 1] + x.y * vs[b + 5] + x.z * vs[b + 9] + x.w * vs[b + 13];
                a2 += x.x * vs[b + 2] + x.y * vs[b + 6] + x.z * vs[b + 10] + x.w * vs[b + 14];
                a3 += x.x * vs[b + 3] + x.y * vs[b + 7] + x.z * vs[b + 11] + x.w * vs[b + 15];
            }
            float4 o; o.x = a0; o.y = a1; o.z = a2; o.w = a3;
            *(float4*)(extraU + (size_t)e * 4) = o;
        }
    } else if (vb < HB + GB128) {
        int b = vb - HB;
        gemm_body<128>(A, Bt, featq, y, elr, NN, b % 11, b / 11);
    } else {
        scan_body(counts, off, cur, nodeperm);
    }
}

// fill: permute ssrc + precomputed extraU into CSR order (16B per edge)
__global__ __launch_bounds__(256) void fill_extra(const int* __restrict__ src,
                                                  const int* __restrict__ dst,
                                                  int* __restrict__ cur,
                                                  const float* __restrict__ extraU,
                                                  int* __restrict__ ssrc,
                                                  float* __restrict__ extra, int E) {
    int e = blockIdx.x * 256 + threadIdx.x;
    if (e >= E) return;
    int p = atomicAdd(&cur[dst[e]], 1);
    ssrc[p] = src[e];
    *(float4*)(extra + (size_t)p * 4) = *(const float4*)(extraU + (size_t)e * 4);
}

// -------------------- gather accumulators: SSA vector values, by-value.
// (R2 lesson: float acc[16] passed as float* failed SROA -> scratch ->
//  620MB/dispatch of spill traffic. Never pass local arrays by pointer.)
__device__ __forceinline__ f32x8 accum8q(f32x8 a, uint2 v, float w) {
    f32x2 p;
    p = __builtin_amdgcn_cvt_pk_f32_fp8(v.x, false); a[0] += w * p.x; a[1] += w * p.y;
    p = __builtin_amdgcn_cvt_pk_f32_fp8(v.x, true);  a[2] += w * p.x; a[3] += w * p.y;
    p = __builtin_amdgcn_cvt_pk_f32_fp8(v.y, false); a[4] += w * p.x; a[5] += w * p.y;
    p = __builtin_amdgcn_cvt_pk_f32_fp8(v.y, true);  a[6] += w * p.x; a[7] += w * p.y;
    return a;
}
__device__ __forceinline__ f32x16 accum16q(f32x16 a, uint4 v, float w) {
    f32x2 p;
    p = __builtin_amdgcn_cvt_pk_f32_fp8(v.x, false); a[0] += w * p.x; a[1] += w * p.y;
    p = __builtin_amdgcn_cvt_pk_f32_fp8(v.x, true);  a[2] += w * p.x; a[3] += w * p.y;
    p = __builtin_amdgcn_cvt_pk_f32_fp8(v.y, false); a[4] += w * p.x; a[5] += w * p.y;
    p = __builtin_amdgcn_cvt_pk_f32_fp8(v.y, true);  a[6] += w * p.x; a[7] += w * p.y;
    p = __builtin_amdgcn_cvt_pk_f32_fp8(v.z, false); a[8] += w * p.x; a[9] += w * p.y;
    p = __builtin_amdgcn_cvt_pk_f32_fp8(v.z, true);  a[10] += w * p.x; a[11] += w * p.y;
    p = __builtin_amdgcn_cvt_pk_f32_fp8(v.w, false); a[12] += w * p.x; a[13] += w * p.y;
    p = __builtin_amdgcn_cvt_pk_f32_fp8(v.w, true);  a[14] += w * p.x; a[15] += w * p.y;
    return a;
}

// ---------------- transposed (h,j) softmax for deg<=64, returned by value.
struct SM64 { float ev0, ev1, ev2, ev3; int sx0, sx1, sx2, sx3; float sc; };

template <bool HAS_EXTRA>
__device__ __forceinline__ SM64 softmax64(int r0, int deg, int h, int jh, float erh,
                                          const float* __restrict__ elr,
                                          const float* __restrict__ extra,
                                          const int* __restrict__ ssrc) {
    SM64 R;
    float a0 = -1e30f, a1 = -1e30f, a2 = -1e30f, a3 = -1e30f;
    int sx0 = 0, sx1 = 0, sx2 = 0, sx3 = 0;
    auto lg = [&](int j, int& sx, float& a) {
        if (j < deg) {
            int idx = r0 + j;
            sx = ssrc[idx];
            float v = elr[(size_t)sx * 8 + h] + erh;
            if (HAS_EXTRA) v += extra[(size_t)idx * 4 + h];
            a = v > 0.f ? v : 0.2f * v;
        }
    };
    lg(jh, sx0, a0);
    if (deg > 16) lg(jh + 16, sx1, a1);
    if (deg > 32) lg(jh + 32, sx2, a2);
    if (deg > 48) lg(jh + 48, sx3, a3);
    float m = fmaxf(fmaxf(a0, a1), fmaxf(a2, a3));
    #pragma unroll
    for (int o = 1; o < 16; o <<= 1) m = fmaxf(m, __shfl_xor(m, o));
    R.ev0 = __expf(a0 - m); R.ev1 = __expf(a1 - m);
    R.ev2 = __expf(a2 - m); R.ev3 = __expf(a3 - m);
    float ss = R.ev0 + R.ev1 + R.ev2 + R.ev3;
    #pragma unroll
    for (int o = 1; o < 16; o <<= 1) ss += __shfl_xor(ss, o);
    R.sc = 0.25f / (ss + 1e-9f);
    R.sx0 = sx0; R.sx1 = sx1; R.sx2 = sx2; R.sx3 = sx3;
    return R;
}

// ---------------- D=128 layers: 1 wave/node; slot-blocked gather (R3/R6
// proven form); node order degree-sorted via nodeperm.
template <bool HAS_EXTRA>
__global__ __launch_bounds__(256) void gat128(const unsigned char* __restrict__ featq,
                                              const float* __restrict__ elr,
                                              const float* __restrict__ extra,
                                              const int* __restrict__ ssrc,
                                              const int* __restrict__ off,
                                              const int* __restrict__ nodeperm,
                                              const float* __restrict__ yres,
                                              short* __restrict__ ybf) {
    int wv = threadIdx.x >> 6, ln = threadIdx.x & 63;
    int n = nodeperm[blockIdx.x * 4 + wv];
    int r0 = off[n], deg = off[n + 1] - r0;
    int h = ln >> 4, jh = ln & 15;
    float erh = elr[(size_t)n * 8 + 4 + h];
    f32x8 acc = {};
    const unsigned char* basep = featq + ln * 8;
    float sc;

    if (deg <= 64) {
        SM64 R = softmax64<HAS_EXTRA>(r0, deg, h, jh, erh, elr, extra, ssrc);
        sc = R.sc;
        int hh = h << 4;
        auto blk16 = [&](float ee, int si, int cnt) {  // cnt in [1,16]
            int c = 0;
            for (; c + 4 <= cnt; c += 4) {
                float w0 = __shfl(ee, hh | c),       w1 = __shfl(ee, hh | (c + 1));
                float w2 = __shfl(ee, hh | (c + 2)), w3 = __shfl(ee, hh | (c + 3));
                int s0 = __shfl(si, c),     s1 = __shfl(si, c + 1);
                int s2 = __shfl(si, c + 2), s3 = __shfl(si, c + 3);
                uint2 v0 = *(const uint2*)(basep + (size_t)s0 * 512);
                uint2 v1 = *(const uint2*)(basep + (size_t)s1 * 512);
                uint2 v2 = *(const uint2*)(basep + (size_t)s2 * 512);
                uint2 v3 = *(const uint2*)(basep + (size_t)s3 * 512);
                acc = accum8q(acc, v0, w0); acc = accum8q(acc, v1, w1);
                acc = accum8q(acc, v2, w2); acc = accum8q(acc, v3, w3);
            }
            for (; c < cnt; ++c) {
                float w = __shfl(ee, hh | c);
                int s = __shfl(si, c);
                uint2 v = *(const uint2*)(basep + (size_t)s * 512);
                acc = accum8q(acc, v, w);
            }
        };
        blk16(R.ev0, R.sx0, deg < 16 ? deg : 16);
        if (deg > 16) blk16(R.ev1, R.sx1, deg < 32 ? deg - 16 : 16);
        if (deg > 32) blk16(R.ev2, R.sx2, deg < 48 ? deg - 32 : 16);
        if (deg > 48) blk16(R.ev3, R.sx3, deg - 48);
    } else {
        // generic fallback (deg>64, effectively never)
        auto lgt = [&](int c) {
            int s = ssrc[r0 + c];
            float v = elr[(size_t)s * 8 + h] + erh;
            if (HAS_EXTRA) v += extra[(size_t)(r0 + c) * 4 + h];
            return v > 0.f ? v : 0.2f * v;
        };
        float m = -1e30f;
        for (int c = 0; c < deg; ++c) m = fmaxf(m, lgt(c));
        float ss = 0.f;
        for (int c = 0; c < deg; ++c) ss += __expf(lgt(c) - m);
        sc = 0.25f / (ss + 1e-9f);
        for (int c = 0; c < deg; ++c) {
            float w = __expf(lgt(c) - m);
            int s = ssrc[r0 + c];
            uint2 v = *(const uint2*)(basep + (size_t)s * 512);
            acc = accum8q(acc, v, w);
        }
    }

    // sc is per-lane correct head scale; head-mean = sum over lanes ^16,^32
    f32x8 t;
    #pragma unroll
    for (int i = 0; i < 8; ++i) {
        float v = acc[i] * sc;
        v += __shfl_xor(v, 16);
        v += __shfl_xor(v, 32);
        t[i] = v;
    }
    if (ln < 16) {
        const float* yr = yres + (size_t)n * 128 + ln * 8;
        float4 y0 = *(const float4*)yr;
        float4 y1 = *(const float4*)(yr + 4);
        float o0 = fmaxf(y0.x + t[0], 0.f), o1 = fmaxf(y0.y + t[1], 0.f);
        float o2 = fmaxf(y0.z + t[2], 0.f), o3 = fmaxf(y0.w + t[3], 0.f);
        float o4 = fmaxf(y1.x + t[4], 0.f), o5 = fmaxf(y1.y + t[5], 0.f);
        float o6 = fmaxf(y1.z + t[6], 0.f), o7 = fmaxf(y1.w + t[7], 0.f);
        uint4 pa;
        pa.x = (unsigned short)f2b(o0) | ((unsigned)(unsigned short)f2b(o1) << 16);
        pa.y = (unsigned short)f2b(o2) | ((unsigned)(unsigned short)f2b(o3) << 16);
        pa.z = (unsigned short)f2b(o4) | ((unsigned)(unsigned short)f2b(o5) << 16);
        pa.w = (unsigned short)f2b(o6) | ((unsigned)(unsigned short)f2b(o7) << 16);
        *(uint4*)(ybf + (size_t)n * 128 + ln * 8) = pa;
    }
}

// ---------------- D=256 layer 4: 2 waves/node (even/odd edges), transposed
// softmax per wave, slot-blocked gather, 16B/lane row, halves via padded LDS.
// Node order degree-sorted via nodeperm.
__global__ __launch_bounds__(256) void gat256(const unsigned char* __restrict__ featq,
                                              const float* __restrict__ elr,
                                              const int* __restrict__ ssrc,
                                              const int* __restrict__ off,
                                              const int* __restrict__ nodeperm,
                                              const float* __restrict__ yres,
                                              float* __restrict__ yout) {
    __shared__ float red[2][16 * 17];
    int wv = threadIdx.x >> 6, ln = threadIdx.x & 63;
    int slot = wv >> 1, half = wv & 1;
    int n = nodeperm[blockIdx.x * 2 + slot];
    int r0 = off[n], deg = off[n + 1] - r0;
    int h = ln >> 4, jh = ln & 15;
    float erh = elr[(size_t)n * 8 + 4 + h];
    f32x16 acc = {};
    const unsigned char* basep = featq + ln * 16;
    float sc;

    if (deg <= 64) {
        SM64 R = softmax64<false>(r0, deg, h, jh, erh, elr, nullptr, ssrc);
        sc = R.sc;
        int hh = h << 4;
        auto blk16 = [&](float ee, int si, int cnt) {  // edges half,half+2,.. < cnt
            int c = half;
            for (; c + 6 < cnt; c += 8) {
                float w0 = __shfl(ee, hh | c),       w1 = __shfl(ee, hh | (c + 2));
                float w2 = __shfl(ee, hh | (c + 4)), w3 = __shfl(ee, hh | (c + 6));
                int s0 = __shfl(si, c),     s1 = __shfl(si, c + 2);
                int s2 = __shfl(si, c + 4), s3 = __shfl(si, c + 6);
                uint4 v0 = *(const uint4*)(basep + (size_t)s0 * 1024);
                uint4 v1 = *(const uint4*)(basep + (size_t)s1 * 1024);
                uint4 v2 = *(const uint4*)(basep + (size_t)s2 * 1024);
                uint4 v3 = *(const uint4*)(basep + (size_t)s3 * 1024);
                acc = accum16q(acc, v0, w0); acc = accum16q(acc, v1, w1);
                acc = accum16q(acc, v2, w2); acc = accum16q(acc, v3, w3);
            }
            for (; c < cnt; c += 2) {
                float w = __shfl(ee, hh | c);
                int s = __shfl(si, c);
                uint4 v = *(const uint4*)(basep + (size_t)s * 1024);
                acc = accum16q(acc, v, w);
            }
        };
        blk16(R.ev0, R.sx0, deg < 16 ? deg : 16);
        if (deg > 16) blk16(R.ev1, R.sx1, (deg < 32 ? deg : 32) - 16);
        if (deg > 32) blk16(R.ev2, R.sx2, (deg < 48 ? deg : 48) - 32);
        if (deg > 48) blk16(R.ev3, R.sx3, deg - 48);
    } else {
        auto lgt = [&](int c) {
            int s = ssrc[r0 + c];
            float v = elr[(size_t)s * 8 + h] + erh;
            return v > 0.f ? v : 0.2f * v;
        };
        float m = -1e30f;
        for (int c = 0; c < deg; ++c) m = fmaxf(m, lgt(c));
        float ss = 0.f;
        for (int c = 0; c < deg; ++c) ss += __expf(lgt(c) - m);
        sc = 0.25f / (ss + 1e-9f);
        for (int c = half; c < deg; c += 2) {
            float w = __expf(lgt(c) - m);
            int s = ssrc[r0 + c];
            uint4 v = *(const uint4*)(basep + (size_t)s * 1024);
            acc = accum16q(acc, v, w);
        }
    }

    // per-lane sc is correct for own head; head-mean via xor16+xor32
    f32x16 t;
    #pragma unroll
    for (int i = 0; i < 16; ++i) {
        float v = acc[i] * sc;
        v += __shfl_xor(v, 16);
        v += __shfl_xor(v, 32);
        t[i] = v;
    }
    if (half == 1 && ln < 16) {
        #pragma unroll
        for (int i = 0; i < 16; ++i) red[slot][ln * 17 + i] = t[i];
    }
    __syncthreads();
    if (half == 0 && ln < 16) {
        const float* yr = yres + (size_t)n * 256 + ln * 16;
        float* yo = yout + (size_t)n * 256 + ln * 16;
        #pragma unroll
        for (int q = 0; q < 4; ++q) {
            float4 ya = *(const float4*)(yr + 4 * q);
            float4 ov;
            ov.x = fmaxf(ya.x + t[4 * q + 0] + red[slot][ln * 17 + 4 * q + 0], 0.f);
            ov.y = fmaxf(ya.y + t[4 * q + 1] + red[slot][ln * 17 + 4 * q + 1], 0.f);
            ov.z = fmaxf(ya.z + t[4 * q + 2] + red[slot][ln * 17 + 4 * q + 2], 0.f);
            ov.w = fmaxf(ya.w + t[4 * q + 3] + red[slot][ln * 17 + 4 * q + 3], 0.f);
            *(float4*)(yo + 4 * q) = ov;
        }
    }
}

// ---------------------------------------------------------------- host side
extern "C" void kernel_launch(void* const* d_in, const int* in_sizes, int n_in,
                              void* d_out, int out_size, void* d_ws, size_t ws_size,
                              hipStream_t stream) {
    const float* node_feats = (const float*)d_in[0];
    const float* edge_feats = (const float*)d_in[1];
    const int*   src        = (const int*)d_in[2];
    const int*   dst        = (const int*)d_in[3];
    const float* W1   = (const float*)d_in[4];
    const float* We1  = (const float*)d_in[5];
    const float* al1  = (const float*)d_in[6];
    const float* ar1  = (const float*)d_in[7];
    const float* ae1  = (const float*)d_in[8];
    const float* res1 = (const float*)d_in[9];
    const float* W2   = (const float*)d_in[10];
    const float* al2  = (const float*)d_in[11];
    const float* ar2  = (const float*)d_in[12];
    const float* res2 = (const float*)d_in[13];
    const float* W3   = (const float*)d_in[14];
    const float* al3  = (const float*)d_in[15];
    const float* ar3  = (const float*)d_in[16];
    const float* res3 = (const float*)d_in[17];
    const float* W4   = (const float*)d_in[18];
    const float* al4  = (const float*)d_in[19];
    const float* ar4  = (const float*)d_in[20];
    const float* res4 = (const float*)d_in[21];

    char* ws = (char*)d_ws;
    auto alloc = [&](size_t bytes) -> char* {
        char* p = ws;
        ws += (bytes + 255) & ~(size_t)255;
        return p;
    };
    int*   counts  = (int*)alloc((size_t)NN * 4);
    int*   offsets = (int*)alloc((size_t)(NN + 1) * 4);
    int*   cursor  = (int*)alloc((size_t)(NN + 1) * 4);
    int*   nodeperm = (int*)alloc((size_t)NN * 4);
    int*   ssrc    = (int*)alloc((size_t)EE * 4);
    unsigned char* featq = (unsigned char*)alloc((size_t)NN * 1024);
    float* xA      = (float*)alloc((size_t)NN * 128 * 4);
    short* xb      = (short*)alloc((size_t)NN * 128 * 2);
    float* elr     = (float*)alloc((size_t)NN * 8 * 4);
    float* extra   = (float*)alloc((size_t)EE * 4 * 4);
    float* extraU  = (float*)alloc((size_t)EE * 4 * 4);
    float* vbuf    = (float*)alloc(1024);
    short* Wc1     = (short*)alloc((size_t)704 * 128 * 2);
    short* Wc2     = (short*)alloc((size_t)704 * 128 * 2);
    short* Wc3     = (short*)alloc((size_t)704 * 128 * 2);
    short* Wc4     = (short*)alloc((size_t)1344 * 128 * 2);

    PrepParams P;
    P.tsrc[0] = W1;   P.tdst[0] = Wc1;              P.tN[0] = 512;  P.tshift[0] = 9;
    P.tsrc[1] = W2;   P.tdst[1] = Wc2;              P.tN[1] = 512;  P.tshift[1] = 9;
    P.tsrc[2] = W3;   P.tdst[2] = Wc3;              P.tN[2] = 512;  P.tshift[2] = 9;
    P.tsrc[3] = W4;   P.tdst[3] = Wc4;              P.tN[3] = 1024; P.tshift[3] = 10;
    P.tsrc[4] = res1; P.tdst[4] = Wc1 + 512 * 128;  P.tN[4] = 128;  P.tshift[4] = 7;
    P.tsrc[5] = res2; P.tdst[5] = Wc2 + 512 * 128;  P.tN[5] = 128;  P.tshift[5] = 7;
    P.tsrc[6] = res3; P.tdst[6] = Wc3 + 512 * 128;  P.tN[6] = 128;  P.tshift[6] = 7;
    P.tsrc[7] = res4; P.tdst[7] = Wc4 + 1024 * 128; P.tN[7] = 256;  P.tshift[7] = 8;
    P.tcum4[0] = 0;
    for (int i = 0; i < 8; ++i) P.tcum4[i + 1] = P.tcum4[i] + P.tN[i] * 128 / 4;
    P.W[0] = W1; P.W[1] = W2; P.W[2] = W3; P.W[3] = W4;
    P.al[0] = al1; P.al[1] = al2; P.al[2] = al3; P.al[3] = al4;
    P.ar[0] = ar1; P.ar[1] = ar2; P.ar[2] = ar3; P.ar[3] = ar4;
    P.Wc[0] = Wc1; P.Wc[1] = Wc2; P.Wc[2] = Wc3; P.Wc[3] = Wc4;
    P.Dl[0] = 128; P.Dl[1] = 128; P.Dl[2] = 128; P.Dl[3] = 256;
    P.base[0] = 640; P.base[1] = 640; P.base[2] = 640; P.base[3] = 1280;
    P.We1 = We1; P.ae1 = ae1; P.vbuf = vbuf;
    P.node_feats = node_feats; P.xb = xb;
    P.dst = dst; P.counts = counts;
    P.bWA = (P.tcum4[8] + 255) / 256;
    P.bV  = P.bWA + 512;
    P.bC  = P.bV + 16;
    P.bZ  = P.bC + (NN * 32 + 255) / 256;
    P.nblk = P.bZ + HB;  // hist blocks replace the old counts-zero blocks

    float* out = (float*)d_out;

    // counts zeroed by memset (graph-capturable); hist hides inside prep
    hipMemsetAsync(counts, 0, (size_t)NN * 4, stream);
    prep_kernel<<<P.nblk, 256, 0, stream>>>(P);
    gemm1_extra_scan<<<HB + GB128 + 1, 256, 0, stream>>>(
        edge_feats, vbuf, extraU, xb, Wc1, featq, xA, elr, counts, offsets, cursor,
        nodeperm);
    fill_extra<<<HB, 256, 0, stream>>>(src, dst, cursor, extraU, ssrc, extra, EE);

    dim3 g128(11, GYR);
    dim3 g256(21, GYR);
    // ---- layer 1 gather
    gat128<true><<<NN / 4, 256, 0, stream>>>(featq, elr, extra, ssrc, offsets,
                                             nodeperm, xA, xb);
    // ---- layer 2
    gemm_fused<128><<<g128, 256, 0, stream>>>(xb, Wc2, featq, xA, elr, NN);
    gat128<false><<<NN / 4, 256, 0, stream>>>(featq, elr, nullptr, ssrc, offsets,
                                              nodeperm, xA, xb);
    // ---- layer 3
    gemm_fused<128><<<g128, 256, 0, stream>>>(xb, Wc3, featq, xA, elr, NN);
    gat128<false><<<NN / 4, 256, 0, stream>>>(featq, elr, nullptr, ssrc, offsets,
                                              nodeperm, xA, xb);
    // ---- layer 4
    gemm_fused<256><<<g256, 256, 0, stream>>>(xb, Wc4, featq, out, elr, NN);
    gat256<<<NN / 2, 256, 0, stream>>>(featq, elr, ssrc, offsets, nodeperm, out, out);
}